// Round 1
// baseline (381.819 us; speedup 1.0000x reference)
//
#include <hip/hip_runtime.h>
#include <hip/hip_bf16.h>
#include <math.h>

#define V 32000
#define E 512
#define H 512
#define N 64
#define L 128
#define NV (N*V)
#define NH (N*H)
#define MTOT (N*L)   // 8192 rows of the score GEMM
#define VT 500       // v-tiles (of 64) in k_logits

typedef short  s8v  __attribute__((ext_vector_type(8)));   // 8 bf16 (4 VGPRs)
typedef float  f4v  __attribute__((ext_vector_type(4)));

__device__ __forceinline__ float sigf(float x) { return 1.0f / (1.0f + __expf(-x)); }

// fp32 -> bf16 round-to-nearest-even (scalar path, non-hot kernels)
__device__ __forceinline__ unsigned short f2bf(float f) {
    unsigned int u = __float_as_uint(f);
    unsigned int r = u + 0x7FFFu + ((u >> 16) & 1u);
    return (unsigned short)(r >> 16);
}

// pair fp32 -> packed 2xbf16, RNE; compiler fuses to v_cvt_pk_bf16_f32
__device__ __forceinline__ unsigned int cvt2bf(float x, float y) {
    __hip_bfloat162 h2 = __float22bfloat162_rn(make_float2(x, y));
    unsigned int r;
    __builtin_memcpy(&r, &h2, 4);
    return r;
}

// 8 fp32 -> one bf16 MFMA fragment
__device__ __forceinline__ s8v pack_bf8(float4 lo, float4 hi) {
    union { unsigned int u[4]; s8v s; } r;
    r.u[0] = cvt2bf(lo.x, lo.y);
    r.u[1] = cvt2bf(lo.z, lo.w);
    r.u[2] = cvt2bf(hi.x, hi.y);
    r.u[3] = cvt2bf(hi.z, hi.w);
    return r.s;
}

__device__ __forceinline__ s8v as_s8v(uint4 q) {
    union { uint4 q; s8v s; } u; u.q = q; return u.s;
}

// ---------------------------------------------------------------------------
// K1: LSTM gate GEMM, k-split partials. grid (32 j-tiles, 8 k-splits of 128),
// block 256 = 64 j-lanes x 4 n-groups(16 n). LDS 32 KB.  (unchanged)
// ---------------------------------------------------------------------------
__global__ __launch_bounds__(256) void k_gates(
    const int* __restrict__ ids, const float* __restrict__ hprev,
    const float* __restrict__ embW, const float* __restrict__ w_ih,
    const float* __restrict__ w_hh, float* __restrict__ gates_p)
{
    __shared__ __align__(16) float xs[64 * 128];  // 32 KB
    const int bx = blockIdx.x;   // j-tile
    const int ks = blockIdx.y;   // k-split (0..7): 0-3 emb, 4-7 h
    const int tid = threadIdx.x;
    const bool emb_part = (ks < 4);
    const int koff = (ks & 3) * 128;

    for (int i = tid; i < 64 * 32; i += 256) {
        int n = i >> 5, kk4 = i & 31;
        float4 x4;
        if (emb_part)
            x4 = ((const float4*)(embW + (size_t)ids[n] * E + koff))[kk4];
        else
            x4 = ((const float4*)(hprev + (size_t)n * H + koff))[kk4];
        ((float4*)xs)[n * 32 + kk4] = x4;
    }
    __syncthreads();

    const int jl = tid & 63;
    const int ng = tid >> 6;
    const int j = bx * 64 + jl;
    const int nb = ng * 16;
    const float* wrow = (emb_part ? w_ih : w_hh) + (size_t)j * 512 + koff;

    float acc[16];
#pragma unroll
    for (int i = 0; i < 16; ++i) acc[i] = 0.f;

    for (int e4 = 0; e4 < 32; ++e4) {
        float4 w4 = ((const float4*)wrow)[e4];
#pragma unroll
        for (int i = 0; i < 16; ++i) {
            float4 x4 = ((const float4*)xs)[(nb + i) * 32 + e4];  // wave-uniform broadcast
            acc[i] += w4.x * x4.x + w4.y * x4.y + w4.z * x4.z + w4.w * x4.w;
        }
    }
#pragma unroll
    for (int i = 0; i < 16; ++i)
        gates_p[(size_t)ks * (64 * 2048) + (size_t)(nb + i) * 2048 + j] = acc[i];
}

// ---------------------------------------------------------------------------
// K1b: combine partials + biases, LSTM pointwise.  (unchanged)
// ---------------------------------------------------------------------------
__global__ __launch_bounds__(256) void k_lstm_pw(
    const float* __restrict__ gates_p, const float* __restrict__ b_ih,
    const float* __restrict__ b_hh, const float* __restrict__ cprev,
    float* __restrict__ out, unsigned short* __restrict__ xb)
{
    int i = blockIdx.x * 256 + threadIdx.x;  // 0..32767
    if (i >= NH) return;
    int n = i >> 9, k = i & 511;
    float g[4];
#pragma unroll
    for (int q = 0; q < 4; ++q) {
        int j = q * 512 + k;
        float s = b_ih[j] + b_hh[j];
#pragma unroll
        for (int ks = 0; ks < 8; ++ks)
            s += gates_p[(size_t)ks * (64 * 2048) + (size_t)n * 2048 + j];
        g[q] = s;
    }
    float ig = sigf(g[0]), fg = sigf(g[1]), gg = tanhf(g[2]), og = sigf(g[3]);
    float ct = fg * cprev[i] + ig * gg;
    float ht = og * tanhf(ct);
    out[NV + i] = ht;
    out[NV + NH + i] = ct;
    xb[(size_t)n * 1024 + k] = f2bf(ht);
}

// ---------------------------------------------------------------------------
// K2a: sproj = h_t @ Wh.T  (64 x 512, K=512). grid 128, block 256. (unchanged)
// ---------------------------------------------------------------------------
__global__ __launch_bounds__(256) void k_sproj(
    const float* __restrict__ out, const float* __restrict__ Wh,
    float* __restrict__ sproj)
{
    __shared__ __align__(16) float xs[512];
    int n = blockIdx.x >> 1;
    int h = (blockIdx.x & 1) * 256 + threadIdx.x;
    const float* ht = out + NV + (size_t)n * 512;
    for (int i = threadIdx.x; i < 512; i += 256) xs[i] = ht[i];
    __syncthreads();
    const float* wrow = Wh + (size_t)h * 512;
    float acc = 0.f;
    for (int e4 = 0; e4 < 128; ++e4) {
        float4 w4 = ((const float4*)wrow)[e4];
        float4 x4 = ((const float4*)xs)[e4];
        acc += w4.x * x4.x + w4.y * x4.y + w4.z * x4.z + w4.w * x4.w;
    }
    sproj[(size_t)n * 512 + h] = acc;
}

// ---------------------------------------------------------------------------
// K2b: score GEMM via bf16 MFMA, v2: LDS-free operands. Each lane loads its
// MFMA fragment directly from global (fp32 -> bf16 in-reg, cvt_pk). No
// per-K-step barriers; register prefetch pipelines the K loop.
// grid (128 m-tiles, 8 h-tiles), block 256.
// ---------------------------------------------------------------------------
__global__ __launch_bounds__(256) void k_score_gemm(
    const float* __restrict__ enc, const float* __restrict__ Ws,
    const float* __restrict__ sproj, const float* __restrict__ av,
    float* __restrict__ scorep)
{
    __shared__ float sred[64];

    const int bm = blockIdx.x, bh = blockIdx.y;
    const int tid = threadIdx.x;
    const int w = tid >> 6, l = tid & 63;
    const int wave_m = (w >> 1) * 32, wave_h = (w & 1) * 32;
    const int lq = l >> 4, lr = l & 15;

    if (tid < 64) sred[tid] = 0.f;

    const float* aP[2];
    aP[0] = enc + (size_t)(bm * 64 + wave_m + lr) * 512 + lq * 8;
    aP[1] = aP[0] + 16 * 512;
    const float* bP[2];
    bP[0] = Ws + (size_t)(bh * 64 + wave_h + lr) * 512 + lq * 8;
    bP[1] = bP[0] + 16 * 512;

    f4v acc[2][2];
#pragma unroll
    for (int i = 0; i < 2; ++i)
#pragma unroll
        for (int j = 0; j < 2; ++j) acc[i][j] = (f4v)0.f;

    float4 ra[2][2][2], rb[2][2][2];   // [frag][ks][half]
#pragma unroll
    for (int i = 0; i < 2; ++i)
#pragma unroll
        for (int ks = 0; ks < 2; ++ks) {
            ra[i][ks][0] = *(const float4*)(aP[i] + ks * 32);
            ra[i][ks][1] = *(const float4*)(aP[i] + ks * 32 + 4);
            rb[i][ks][0] = *(const float4*)(bP[i] + ks * 32);
            rb[i][ks][1] = *(const float4*)(bP[i] + ks * 32 + 4);
        }

#pragma unroll 1
    for (int kt = 0; kt < 8; ++kt) {
        s8v a_frag[2][2], b_frag[2][2];
#pragma unroll
        for (int i = 0; i < 2; ++i)
#pragma unroll
            for (int ks = 0; ks < 2; ++ks) {
                a_frag[i][ks] = pack_bf8(ra[i][ks][0], ra[i][ks][1]);
                b_frag[i][ks] = pack_bf8(rb[i][ks][0], rb[i][ks][1]);
            }

        if (kt < 7) {
            const int off = (kt + 1) * 64;
#pragma unroll
            for (int i = 0; i < 2; ++i)
#pragma unroll
                for (int ks = 0; ks < 2; ++ks) {
                    ra[i][ks][0] = *(const float4*)(aP[i] + off + ks * 32);
                    ra[i][ks][1] = *(const float4*)(aP[i] + off + ks * 32 + 4);
                    rb[i][ks][0] = *(const float4*)(bP[i] + off + ks * 32);
                    rb[i][ks][1] = *(const float4*)(bP[i] + off + ks * 32 + 4);
                }
        }

#pragma unroll
        for (int ks = 0; ks < 2; ++ks)
#pragma unroll
            for (int i = 0; i < 2; ++i)
#pragma unroll
                for (int j = 0; j < 2; ++j)
                    acc[i][j] = __builtin_amdgcn_mfma_f32_16x16x32_bf16(
                        a_frag[i][ks], b_frag[j][ks], acc[i][j], 0, 0, 0);
    }
    __syncthreads();   // sred init visible before atomics

    const int hc0 = bh * 64 + wave_h + lr;
#pragma unroll
    for (int i = 0; i < 2; ++i) {
#pragma unroll
        for (int reg = 0; reg < 4; ++reg) {
            int m_local = wave_m + 16 * i + lq * 4 + reg;
            int m = bm * 64 + m_local;
            int n = m >> 7;
            float p = 0.f;
#pragma unroll
            for (int j = 0; j < 2; ++j) {
                int hc = hc0 + 16 * j;
                float val = acc[i][j][reg] + sproj[(size_t)n * 512 + hc];
                p += tanhf(val) * av[hc];
            }
            p += __shfl_xor(p, 1, 64);
            p += __shfl_xor(p, 2, 64);
            p += __shfl_xor(p, 4, 64);
            p += __shfl_xor(p, 8, 64);
            if (lr == 0) atomicAdd(&sred[m_local], p);
        }
    }
    __syncthreads();
    if (tid < 64)
        scorep[(size_t)bh * MTOT + bm * 64 + tid] = sred[tid];
}

// ---------------------------------------------------------------------------
// K2c v2: combine score partials, mask, softmax over L, context. 4-way split
// over H for memory parallelism (softmax recomputed redundantly per block).
// grid (64 n, 4 h-chunks), block 128.
// ---------------------------------------------------------------------------
__global__ __launch_bounds__(128) void k_softmax_ctx(
    const float* __restrict__ scorep, const unsigned char* __restrict__ mask,
    const float* __restrict__ enc, unsigned short* __restrict__ xb)
{
    __shared__ float wl[128];
    __shared__ float red[4];
    const int n = blockIdx.x, hc = blockIdx.y, t = threadIdx.x;  // t = l index

    float s = 0.f;
#pragma unroll
    for (int q = 0; q < 8; ++q)
        s += scorep[(size_t)q * MTOT + n * 128 + t];
    if (mask[(size_t)n * 128 + t]) s = -1e30f;

    float m = s;
#pragma unroll
    for (int off = 32; off > 0; off >>= 1) m = fmaxf(m, __shfl_xor(m, off, 64));
    if ((t & 63) == 0) red[t >> 6] = m;
    __syncthreads();
    m = fmaxf(red[0], red[1]);
    float e = __expf(s - m);
    float ss = e;
#pragma unroll
    for (int off = 32; off > 0; off >>= 1) ss += __shfl_xor(ss, off, 64);
    if ((t & 63) == 0) red[2 + (t >> 6)] = ss;
    __syncthreads();
    float inv = 1.0f / (red[2] + red[3]);
    wl[t] = e * inv;
    __syncthreads();

    const float* encn = enc + (size_t)n * (L * H) + hc * 128 + t;
    float acc = 0.f;
#pragma unroll 4
    for (int ll = 0; ll < 128; ++ll)
        acc += wl[ll] * encn[(size_t)ll * 512];
    xb[(size_t)n * 1024 + 512 + hc * 128 + t] = f2bf(acc);
}

// ---------------------------------------------------------------------------
// K4a v2: logits GEMM via bf16 MFMA, LDS-free operands. A fragments stream
// straight from h2oW (fp32 -> bf16 cvt_pk in-reg); B fragments are direct
// 16B loads from the bf16 xb buffer (L2-resident). No barriers in the K
// loop; register double-buffer prefetch. LDS only for the output transpose.
// Epilogue unchanged: coalesced stores + per-block log-softmax partials.
// grid 500, block 256 = 4 waves (2x2 of 32x32).
// ---------------------------------------------------------------------------
__global__ __launch_bounds__(256) void k_logits(
    const float* __restrict__ h2oW, const unsigned short* __restrict__ xb,
    const float* __restrict__ h2ob, float* __restrict__ dlogits,
    float* __restrict__ pmax, float* __restrict__ psum)
{
    __shared__ __align__(16) float cs[64 * 68];   // 17408 B (n x v)

    const int bm = blockIdx.x;   // v-tile
    const int tid = threadIdx.x;
    const int w = tid >> 6, l = tid & 63;
    const int wave_m = (w & 1) * 32, wave_n = (w >> 1) * 32;
    const int lq = l >> 4, lr = l & 15;

    const float* aP[2];
    aP[0] = h2oW + (size_t)(bm * 64 + wave_m + lr) * 1024 + lq * 8;
    aP[1] = aP[0] + 16 * 1024;
    const unsigned short* bP[2];
    bP[0] = xb + (size_t)(wave_n + lr) * 1024 + lq * 8;
    bP[1] = bP[0] + 16 * 1024;

    f4v acc[2][2];
#pragma unroll
    for (int i = 0; i < 2; ++i)
#pragma unroll
        for (int j = 0; j < 2; ++j) acc[i][j] = (f4v)0.f;

    float4 ra[2][2][2];   // [i][ks][half]
    uint4  rb[2][2];      // [j][ks] (already bf16)
#pragma unroll
    for (int i = 0; i < 2; ++i)
#pragma unroll
        for (int ks = 0; ks < 2; ++ks) {
            ra[i][ks][0] = *(const float4*)(aP[i] + ks * 32);
            ra[i][ks][1] = *(const float4*)(aP[i] + ks * 32 + 4);
        }
#pragma unroll
    for (int j = 0; j < 2; ++j)
#pragma unroll
        for (int ks = 0; ks < 2; ++ks)
            rb[j][ks] = *(const uint4*)(bP[j] + ks * 32);

#pragma unroll 1
    for (int kt = 0; kt < 16; ++kt) {
        s8v a_frag[2][2], b_frag[2][2];
#pragma unroll
        for (int i = 0; i < 2; ++i)
#pragma unroll
            for (int ks = 0; ks < 2; ++ks)
                a_frag[i][ks] = pack_bf8(ra[i][ks][0], ra[i][ks][1]);
#pragma unroll
        for (int j = 0; j < 2; ++j)
#pragma unroll
            for (int ks = 0; ks < 2; ++ks)
                b_frag[j][ks] = as_s8v(rb[j][ks]);

        if (kt < 15) {
            const int off = (kt + 1) * 64;
#pragma unroll
            for (int i = 0; i < 2; ++i)
#pragma unroll
                for (int ks = 0; ks < 2; ++ks) {
                    ra[i][ks][0] = *(const float4*)(aP[i] + off + ks * 32);
                    ra[i][ks][1] = *(const float4*)(aP[i] + off + ks * 32 + 4);
                }
#pragma unroll
            for (int j = 0; j < 2; ++j)
#pragma unroll
                for (int ks = 0; ks < 2; ++ks)
                    rb[j][ks] = *(const uint4*)(bP[j] + off + ks * 32);
        }

#pragma unroll
        for (int ks = 0; ks < 2; ++ks)
#pragma unroll
            for (int i = 0; i < 2; ++i)
#pragma unroll
                for (int j = 0; j < 2; ++j)
                    acc[i][j] = __builtin_amdgcn_mfma_f32_16x16x32_bf16(
                        a_frag[i][ks], b_frag[j][ks], acc[i][j], 0, 0, 0);
    }

    // transpose through LDS: cs[n_local][v_local]
#pragma unroll
    for (int i = 0; i < 2; ++i)
#pragma unroll
        for (int j = 0; j < 2; ++j)
#pragma unroll
            for (int reg = 0; reg < 4; ++reg)
                cs[(wave_n + 16 * j + lr) * 68 + wave_m + 16 * i + lq * 4 + reg] = acc[i][j][reg];
    __syncthreads();

    // coalesced stores + log-softmax partials
    const int n = tid >> 2, q = tid & 3;
    const int v0 = bm * 64 + q * 16;
    float4 vals[4];
    float m_loc = -1e30f;
#pragma unroll
    for (int k = 0; k < 4; ++k) {
        float4 cv = *(const float4*)(cs + n * 68 + q * 16 + 4 * k);
        float4 bv = *(const float4*)(h2ob + v0 + 4 * k);
        cv.x += bv.x; cv.y += bv.y; cv.z += bv.z; cv.w += bv.w;
        vals[k] = cv;
        *(float4*)(dlogits + (size_t)n * V + v0 + 4 * k) = cv;
        m_loc = fmaxf(m_loc, fmaxf(fmaxf(cv.x, cv.y), fmaxf(cv.z, cv.w)));
    }
    float s_loc = 0.f;
#pragma unroll
    for (int k = 0; k < 4; ++k) {
        s_loc += __expf(vals[k].x - m_loc) + __expf(vals[k].y - m_loc)
               + __expf(vals[k].z - m_loc) + __expf(vals[k].w - m_loc);
    }
    // combine the 4 q-lanes (adjacent lanes) of row n
    float m2 = fmaxf(m_loc, __shfl_xor(m_loc, 1, 64));
    m2 = fmaxf(m2, __shfl_xor(m2, 2, 64));
    s_loc *= __expf(m_loc - m2);
    float s2 = s_loc + __shfl_xor(s_loc, 1, 64);
    s2 += __shfl_xor(s2, 2, 64);
    if (q == 0) {
        pmax[(size_t)n * VT + bm] = m2;
        psum[(size_t)n * VT + bm] = s2;
    }
}

// ---------------------------------------------------------------------------
// K4b: combine per-block partials -> lse[n]. grid 64, block 256. (unchanged)
// ---------------------------------------------------------------------------
__global__ __launch_bounds__(256) void k_lse(
    const float* __restrict__ pmax, const float* __restrict__ psum,
    float* __restrict__ lse)
{
    __shared__ float rm[4], rs[4];
    const int n = blockIdx.x, t = threadIdx.x;
    float m0 = (t < VT) ? pmax[(size_t)n * VT + t] : -1e30f;
    float m1 = (t + 256 < VT) ? pmax[(size_t)n * VT + t + 256] : -1e30f;
    float mm = fmaxf(m0, m1);
#pragma unroll
    for (int off = 32; off > 0; off >>= 1) mm = fmaxf(mm, __shfl_xor(mm, off, 64));
    if ((t & 63) == 0) rm[t >> 6] = mm;
    __syncthreads();
    float m = fmaxf(fmaxf(rm[0], rm[1]), fmaxf(rm[2], rm[3]));

    float s = 0.f;
    if (t < VT)       s += psum[(size_t)n * VT + t] * __expf(m0 - m);
    if (t + 256 < VT) s += psum[(size_t)n * VT + t + 256] * __expf(m1 - m);
#pragma unroll
    for (int off = 32; off > 0; off >>= 1) s += __shfl_xor(s, off, 64);
    if ((t & 63) == 0) rs[t >> 6] = s;
    __syncthreads();
    if (t == 0) {
        float st = rs[0] + rs[1] + rs[2] + rs[3];
        lse[n] = m + __logf(st);
    }
}

// ---------------------------------------------------------------------------
// K4c: normalize logits in place. grid (32, 64), block 256, float4. (unchanged)
// ---------------------------------------------------------------------------
__global__ __launch_bounds__(256) void k_norm(
    float* __restrict__ dlogits, const float* __restrict__ lse)
{
    const int n = blockIdx.y;
    const int t4 = blockIdx.x * 256 + threadIdx.x;   // float4 index in row
    if (t4 >= V / 4) return;
    float s = lse[n];
    float4* p = (float4*)(dlogits + (size_t)n * V) + t4;
    float4 v = *p;
    v.x -= s; v.y -= s; v.z -= s; v.w -= s;
    *p = v;
}

// ---------------------------------------------------------------------------
extern "C" void kernel_launch(void* const* d_in, const int* in_sizes, int n_in,
                              void* d_out, int out_size, void* d_ws, size_t ws_size,
                              hipStream_t stream)
{
    const int* ids   = (const int*)d_in[0];
    const float* h   = (const float*)d_in[1];
    const float* c   = (const float*)d_in[2];
    const float* enc = (const float*)d_in[3];
    const unsigned char* mask = (const unsigned char*)d_in[4];
    const float* embW = (const float*)d_in[5];
    const float* w_ih = (const float*)d_in[6];
    const float* b_ih = (const float*)d_in[7];
    const float* w_hh = (const float*)d_in[8];
    const float* b_hh = (const float*)d_in[9];
    const float* Wh   = (const float*)d_in[10];
    const float* Ws   = (const float*)d_in[11];
    const float* av   = (const float*)d_in[12];
    const float* h2oW = (const float*)d_in[13];
    const float* h2ob = (const float*)d_in[14];

    float* out = (float*)d_out;
    float* ws = (float*)d_ws;
    // layout (floats):
    float* gates_p = ws;                          // 8*64*2048 = 1048576
    float* sproj   = ws + 1048576;                // 32768
    float* scorep  = ws + 1048576 + 32768;        // 65536
    unsigned short* xb = (unsigned short*)(ws + 1048576 + 32768 + 65536);  // 64x1024 bf16
    // pmax/psum/lse overlay the gates_p region (dead after k_lstm_pw)
    float* pmax = ws;                             // 64*500 = 32000
    float* psum = ws + 32000;                     // 32000
    float* lse  = ws + 64000;                     // 64

    k_gates<<<dim3(32, 8), 256, 0, stream>>>(ids, h, embW, w_ih, w_hh, gates_p);
    k_lstm_pw<<<128, 256, 0, stream>>>(gates_p, b_ih, b_hh, c, out, xb);
    k_sproj<<<128, 256, 0, stream>>>(out, Wh, sproj);
    k_score_gemm<<<dim3(128, 8), 256, 0, stream>>>(enc, Ws, sproj, av, scorep);
    k_softmax_ctx<<<dim3(64, 4), 128, 0, stream>>>(scorep, mask, enc, xb);
    k_logits<<<VT, 256, 0, stream>>>(h2oW, xb, h2ob, out, pmax, psum);
    k_lse<<<64, 256, 0, stream>>>(pmax, psum, lse);
    k_norm<<<dim3(32, 64), 256, 0, stream>>>(out, lse);
}

// Round 2
// 351.275 us; speedup vs baseline: 1.0870x; 1.0870x over previous
//
#include <hip/hip_runtime.h>
#include <hip/hip_bf16.h>
#include <math.h>

#define V 32000
#define E 512
#define H 512
#define N 64
#define L 128
#define NV (N*V)
#define NH (N*H)
#define MTOT (N*L)   // 8192 rows of the score GEMM
#define VT 500       // v-tiles (of 64) in k_logits

typedef short  s8v  __attribute__((ext_vector_type(8)));   // 8 bf16 (4 VGPRs)
typedef float  f4v  __attribute__((ext_vector_type(4)));

__device__ __forceinline__ float sigf(float x) { return 1.0f / (1.0f + __expf(-x)); }

// fp32 -> bf16 round-to-nearest-even (scalar path, non-hot kernels)
__device__ __forceinline__ unsigned short f2bf(float f) {
    unsigned int u = __float_as_uint(f);
    unsigned int r = u + 0x7FFFu + ((u >> 16) & 1u);
    return (unsigned short)(r >> 16);
}

// pair fp32 -> packed 2xbf16, RNE; compiler emits v_cvt_pk_bf16_f32
__device__ __forceinline__ unsigned int cvt2bf(float x, float y) {
    __hip_bfloat162 h2 = __float22bfloat162_rn(make_float2(x, y));
    unsigned int r;
    __builtin_memcpy(&r, &h2, 4);
    return r;
}

// 8 fp32 -> 4 packed bf16 pairs (one 16B LDS store)
__device__ __forceinline__ uint4 pack_q(float4 lo, float4 hi) {
    uint4 q;
    q.x = cvt2bf(lo.x, lo.y); q.y = cvt2bf(lo.z, lo.w);
    q.z = cvt2bf(hi.x, hi.y); q.w = cvt2bf(hi.z, hi.w);
    return q;
}

// ---------------------------------------------------------------------------
// K1: LSTM gate GEMM, k-split partials. grid (32 j-tiles, 8 k-splits of 128),
// block 256 = 64 j-lanes x 4 n-groups(16 n). LDS 32 KB.  (R0 verbatim)
// ---------------------------------------------------------------------------
__global__ __launch_bounds__(256) void k_gates(
    const int* __restrict__ ids, const float* __restrict__ hprev,
    const float* __restrict__ embW, const float* __restrict__ w_ih,
    const float* __restrict__ w_hh, float* __restrict__ gates_p)
{
    __shared__ __align__(16) float xs[64 * 128];  // 32 KB
    const int bx = blockIdx.x;   // j-tile
    const int ks = blockIdx.y;   // k-split (0..7): 0-3 emb, 4-7 h
    const int tid = threadIdx.x;
    const bool emb_part = (ks < 4);
    const int koff = (ks & 3) * 128;

    for (int i = tid; i < 64 * 32; i += 256) {
        int n = i >> 5, kk4 = i & 31;
        float4 x4;
        if (emb_part)
            x4 = ((const float4*)(embW + (size_t)ids[n] * E + koff))[kk4];
        else
            x4 = ((const float4*)(hprev + (size_t)n * H + koff))[kk4];
        ((float4*)xs)[n * 32 + kk4] = x4;
    }
    __syncthreads();

    const int jl = tid & 63;
    const int ng = tid >> 6;
    const int j = bx * 64 + jl;
    const int nb = ng * 16;
    const float* wrow = (emb_part ? w_ih : w_hh) + (size_t)j * 512 + koff;

    float acc[16];
#pragma unroll
    for (int i = 0; i < 16; ++i) acc[i] = 0.f;

    for (int e4 = 0; e4 < 32; ++e4) {
        float4 w4 = ((const float4*)wrow)[e4];
#pragma unroll
        for (int i = 0; i < 16; ++i) {
            float4 x4 = ((const float4*)xs)[(nb + i) * 32 + e4];  // wave-uniform broadcast
            acc[i] += w4.x * x4.x + w4.y * x4.y + w4.z * x4.z + w4.w * x4.w;
        }
    }
#pragma unroll
    for (int i = 0; i < 16; ++i)
        gates_p[(size_t)ks * (64 * 2048) + (size_t)(nb + i) * 2048 + j] = acc[i];
}

// ---------------------------------------------------------------------------
// K1b: combine partials + biases, LSTM pointwise.  (R0 verbatim)
// ---------------------------------------------------------------------------
__global__ __launch_bounds__(256) void k_lstm_pw(
    const float* __restrict__ gates_p, const float* __restrict__ b_ih,
    const float* __restrict__ b_hh, const float* __restrict__ cprev,
    float* __restrict__ out, unsigned short* __restrict__ xb)
{
    int i = blockIdx.x * 256 + threadIdx.x;  // 0..32767
    if (i >= NH) return;
    int n = i >> 9, k = i & 511;
    float g[4];
#pragma unroll
    for (int q = 0; q < 4; ++q) {
        int j = q * 512 + k;
        float s = b_ih[j] + b_hh[j];
#pragma unroll
        for (int ks = 0; ks < 8; ++ks)
            s += gates_p[(size_t)ks * (64 * 2048) + (size_t)n * 2048 + j];
        g[q] = s;
    }
    float ig = sigf(g[0]), fg = sigf(g[1]), gg = tanhf(g[2]), og = sigf(g[3]);
    float ct = fg * cprev[i] + ig * gg;
    float ht = og * tanhf(ct);
    out[NV + i] = ht;
    out[NV + NH + i] = ct;
    xb[(size_t)n * 1024 + k] = f2bf(ht);
}

// ---------------------------------------------------------------------------
// K2a: sproj = h_t @ Wh.T  (64 x 512, K=512). grid 128, block 256. (R0 verbatim)
// ---------------------------------------------------------------------------
__global__ __launch_bounds__(256) void k_sproj(
    const float* __restrict__ out, const float* __restrict__ Wh,
    float* __restrict__ sproj)
{
    __shared__ __align__(16) float xs[512];
    int n = blockIdx.x >> 1;
    int h = (blockIdx.x & 1) * 256 + threadIdx.x;
    const float* ht = out + NV + (size_t)n * 512;
    for (int i = threadIdx.x; i < 512; i += 256) xs[i] = ht[i];
    __syncthreads();
    const float* wrow = Wh + (size_t)h * 512;
    float acc = 0.f;
    for (int e4 = 0; e4 < 128; ++e4) {
        float4 w4 = ((const float4*)wrow)[e4];
        float4 x4 = ((const float4*)xs)[e4];
        acc += w4.x * x4.x + w4.y * x4.y + w4.z * x4.z + w4.w * x4.w;
    }
    sproj[(size_t)n * 512 + h] = acc;
}

// ---------------------------------------------------------------------------
// K2b: score GEMM via bf16 MFMA + fused tanh/v-dot epilogue. R0 structure
// (LDS-staged); only change: cvt_pk packing instead of 3-op f2bf.
// grid (128 m-tiles, 8 h-tiles), block 256.
// ---------------------------------------------------------------------------
__global__ __launch_bounds__(256) void k_score_gemm(
    const float* __restrict__ enc, const float* __restrict__ Ws,
    const float* __restrict__ sproj, const float* __restrict__ av,
    float* __restrict__ scorep)
{
    __shared__ __align__(16) short As[64 * 72];
    __shared__ __align__(16) short Bs[64 * 72];
    __shared__ float sred[64];

    const int bm = blockIdx.x, bh = blockIdx.y;
    const int tid = threadIdx.x;
    const int w = tid >> 6, l = tid & 63;
    const int wave_m = (w >> 1) * 32, wave_h = (w & 1) * 32;
    const int lq = l >> 4, lr = l & 15;

    if (tid < 64) sred[tid] = 0.f;

    f4v acc[2][2];
#pragma unroll
    for (int i = 0; i < 2; ++i)
#pragma unroll
        for (int j = 0; j < 2; ++j) acc[i][j] = (f4v)0.f;

    for (int kt = 0; kt < 8; ++kt) {
        __syncthreads();
#pragma unroll
        for (int r = 0; r < 2; ++r) {
            int idx = (r * 256 + tid) * 8;
            int row = idx >> 6, col = idx & 63;
            const float* sa = enc + (size_t)(bm * 64 + row) * 512 + kt * 64 + col;
            const float* sb = Ws  + (size_t)(bh * 64 + row) * 512 + kt * 64 + col;
            float4 a0 = *(const float4*)sa, a1 = *(const float4*)(sa + 4);
            float4 b0 = *(const float4*)sb, b1 = *(const float4*)(sb + 4);
            *(uint4*)(As + row * 72 + col) = pack_q(a0, a1);
            *(uint4*)(Bs + row * 72 + col) = pack_q(b0, b1);
        }
        __syncthreads();

#pragma unroll
        for (int ks = 0; ks < 2; ++ks) {
            s8v a_frag[2], b_frag[2];
#pragma unroll
            for (int i = 0; i < 2; ++i)
                a_frag[i] = *(const s8v*)(As + (wave_m + 16 * i + lr) * 72 + ks * 32 + lq * 8);
#pragma unroll
            for (int j = 0; j < 2; ++j)
                b_frag[j] = *(const s8v*)(Bs + (wave_h + 16 * j + lr) * 72 + ks * 32 + lq * 8);
#pragma unroll
            for (int i = 0; i < 2; ++i)
#pragma unroll
                for (int j = 0; j < 2; ++j)
                    acc[i][j] = __builtin_amdgcn_mfma_f32_16x16x32_bf16(
                        a_frag[i], b_frag[j], acc[i][j], 0, 0, 0);
        }
    }
    __syncthreads();

    const int hc0 = bh * 64 + wave_h + lr;
#pragma unroll
    for (int i = 0; i < 2; ++i) {
#pragma unroll
        for (int reg = 0; reg < 4; ++reg) {
            int m_local = wave_m + 16 * i + lq * 4 + reg;
            int m = bm * 64 + m_local;
            int n = m >> 7;
            float p = 0.f;
#pragma unroll
            for (int j = 0; j < 2; ++j) {
                int hc = hc0 + 16 * j;
                float val = acc[i][j][reg] + sproj[(size_t)n * 512 + hc];
                p += tanhf(val) * av[hc];
            }
            p += __shfl_xor(p, 1, 64);
            p += __shfl_xor(p, 2, 64);
            p += __shfl_xor(p, 4, 64);
            p += __shfl_xor(p, 8, 64);
            if (lr == 0) atomicAdd(&sred[m_local], p);
        }
    }
    __syncthreads();
    if (tid < 64)
        scorep[(size_t)bh * MTOT + bm * 64 + tid] = sred[tid];
}

// ---------------------------------------------------------------------------
// K2c: combine score partials, mask, softmax over L, context; writes bf16
// context into xb[:, 512:1024]. grid 64 (n), block 512.  (R0 verbatim)
// ---------------------------------------------------------------------------
__global__ __launch_bounds__(512) void k_softmax_ctx(
    const float* __restrict__ scorep, const unsigned char* __restrict__ mask,
    const float* __restrict__ enc, unsigned short* __restrict__ xb)
{
    __shared__ float sc[128];
    __shared__ float wl[128];
    const int n = blockIdx.x, t = threadIdx.x;

    if (t < 128) {
        float s = 0.f;
#pragma unroll
        for (int q = 0; q < 8; ++q)
            s += scorep[(size_t)q * MTOT + n * 128 + t];
        if (mask[(size_t)n * 128 + t]) s = -1e30f;
        sc[t] = s;
    }
    __syncthreads();
    if (t < 64) {
        float m = fmaxf(sc[t], sc[t + 64]);
#pragma unroll
        for (int off = 32; off > 0; off >>= 1) m = fmaxf(m, __shfl_xor(m, off, 64));
        float e0 = __expf(sc[t] - m), e1 = __expf(sc[t + 64] - m);
        float ss = e0 + e1;
#pragma unroll
        for (int off = 32; off > 0; off >>= 1) ss += __shfl_xor(ss, off, 64);
        float inv = 1.0f / ss;
        wl[t] = e0 * inv;
        wl[t + 64] = e1 * inv;
    }
    __syncthreads();

    const float* encn = enc + (size_t)n * L * H + t;
    float acc = 0.f;
#pragma unroll 4
    for (int ll = 0; ll < 128; ++ll)
        acc += wl[ll] * encn[(size_t)ll * 512];
    xb[(size_t)n * 1024 + 512 + t] = f2bf(acc);
}

// ---------------------------------------------------------------------------
// K4a: logits GEMM via bf16 MFMA, C^T view: M=v(32000), N=n(64), K=1024.
// grid 500 (v-tiles of 64), block 256 = 4 waves (2x2 of 32x32). BK=64.
// R0 staged-LDS structure, with: (a) cvt_pk bf16 packing, (b) kt unrolled
// by 2 with TWO named register stages -> each global load has ~2 full
// phases in flight before its waitcnt (HBM latency ~900cy covered).
// Epilogue unchanged: LDS transpose -> coalesced stores + log-softmax partials.
// ---------------------------------------------------------------------------
__global__ __launch_bounds__(256) void k_logits(
    const float* __restrict__ h2oW, const unsigned short* __restrict__ xb,
    const float* __restrict__ h2ob, float* __restrict__ dlogits,
    float* __restrict__ pmax, float* __restrict__ psum)
{
    __shared__ __align__(16) short As[64 * 72];   //  9216 B (v x k)
    __shared__ __align__(16) short Bs[64 * 72];   //  9216 B (n x k)
    __shared__ __align__(16) float cs[64 * 68];   // 17408 B (n x v)

    const int bm = blockIdx.x;   // v-tile
    const int tid = threadIdx.x;
    const int w = tid >> 6, l = tid & 63;
    const int wave_m = (w & 1) * 32, wave_n = (w >> 1) * 32;
    const int lq = l >> 4, lr = l & 15;

    const int arow = tid >> 2;            // 0..63
    const int acol = (tid & 3) * 16;      // 0,16,32,48
    const float* aptr = h2oW + (size_t)(bm * 64 + arow) * 1024 + acol;
    const unsigned short* bptr = xb + (size_t)arow * 1024 + acol;

    f4v acc[2][2];
#pragma unroll
    for (int i = 0; i < 2; ++i)
#pragma unroll
        for (int j = 0; j < 2; ++j) acc[i][j] = (f4v)0.f;

    // two named register stages (static indexing only — no runtime-indexed arrays)
    float4 rAa[4]; uint4 rAb[2];   // even K-steps
    float4 rBa[4]; uint4 rBb[2];   // odd  K-steps

#define LOADSTAGE(Ra, Rb, KT)                                              \
    {                                                                      \
        const float* ap = aptr + (KT) * 64;                                \
        const unsigned short* bp = bptr + (KT) * 64;                       \
        Ra[0] = ((const float4*)ap)[0]; Ra[1] = ((const float4*)ap)[1];    \
        Ra[2] = ((const float4*)ap)[2]; Ra[3] = ((const float4*)ap)[3];    \
        Rb[0] = *(const uint4*)bp; Rb[1] = *(const uint4*)(bp + 8);        \
    }

#define PACKSTORE(Ra, Rb)                                                  \
    {                                                                      \
        *(uint4*)(As + arow * 72 + acol)     = pack_q(Ra[0], Ra[1]);       \
        *(uint4*)(As + arow * 72 + acol + 8) = pack_q(Ra[2], Ra[3]);       \
        *(uint4*)(Bs + arow * 72 + acol)     = Rb[0];                      \
        *(uint4*)(Bs + arow * 72 + acol + 8) = Rb[1];                      \
    }

#define MFMA_PHASE()                                                       \
    {                                                                      \
        _Pragma("unroll")                                                  \
        for (int ks = 0; ks < 2; ++ks) {                                   \
            s8v a_frag[2], b_frag[2];                                      \
            _Pragma("unroll")                                              \
            for (int i = 0; i < 2; ++i)                                    \
                a_frag[i] = *(const s8v*)(As + (wave_m + 16 * i + lr) * 72 + ks * 32 + lq * 8); \
            _Pragma("unroll")                                              \
            for (int j = 0; j < 2; ++j)                                    \
                b_frag[j] = *(const s8v*)(Bs + (wave_n + 16 * j + lr) * 72 + ks * 32 + lq * 8); \
            _Pragma("unroll")                                              \
            for (int i = 0; i < 2; ++i)                                    \
                _Pragma("unroll")                                          \
                for (int j = 0; j < 2; ++j)                                \
                    acc[i][j] = __builtin_amdgcn_mfma_f32_16x16x32_bf16(   \
                        a_frag[i], b_frag[j], acc[i][j], 0, 0, 0);         \
        }                                                                  \
    }

    LOADSTAGE(rAa, rAb, 0);
    LOADSTAGE(rBa, rBb, 1);

#pragma unroll 1
    for (int kt = 0; kt < 16; kt += 2) {
        // even phase: consume stage kt, refill for kt+2
        if (kt) __syncthreads();
        PACKSTORE(rAa, rAb);
        if (kt + 2 < 16) LOADSTAGE(rAa, rAb, kt + 2);
        __syncthreads();
        MFMA_PHASE();
        // odd phase: consume stage kt+1, refill for kt+3
        __syncthreads();
        PACKSTORE(rBa, rBb);
        if (kt + 3 < 16) LOADSTAGE(rBa, rBb, kt + 3);
        __syncthreads();
        MFMA_PHASE();
    }
#undef LOADSTAGE
#undef PACKSTORE
#undef MFMA_PHASE
    __syncthreads();

    // transpose through LDS: cs[n_local][v_local]
#pragma unroll
    for (int i = 0; i < 2; ++i)
#pragma unroll
        for (int j = 0; j < 2; ++j)
#pragma unroll
            for (int reg = 0; reg < 4; ++reg)
                cs[(wave_n + 16 * j + lr) * 68 + wave_m + 16 * i + lq * 4 + reg] = acc[i][j][reg];
    __syncthreads();

    // coalesced stores + log-softmax partials
    const int n = tid >> 2, q = tid & 3;
    const int v0 = bm * 64 + q * 16;
    float4 vals[4];
    float m_loc = -1e30f;
#pragma unroll
    for (int k = 0; k < 4; ++k) {
        float4 cv = *(const float4*)(cs + n * 68 + q * 16 + 4 * k);
        float4 bv = *(const float4*)(h2ob + v0 + 4 * k);
        cv.x += bv.x; cv.y += bv.y; cv.z += bv.z; cv.w += bv.w;
        vals[k] = cv;
        *(float4*)(dlogits + (size_t)n * V + v0 + 4 * k) = cv;
        m_loc = fmaxf(m_loc, fmaxf(fmaxf(cv.x, cv.y), fmaxf(cv.z, cv.w)));
    }
    float s_loc = 0.f;
#pragma unroll
    for (int k = 0; k < 4; ++k) {
        s_loc += __expf(vals[k].x - m_loc) + __expf(vals[k].y - m_loc)
               + __expf(vals[k].z - m_loc) + __expf(vals[k].w - m_loc);
    }
    // combine the 4 q-lanes (adjacent lanes) of row n
    float m2 = fmaxf(m_loc, __shfl_xor(m_loc, 1, 64));
    m2 = fmaxf(m2, __shfl_xor(m2, 2, 64));
    s_loc *= __expf(m_loc - m2);
    float s2 = s_loc + __shfl_xor(s_loc, 1, 64);
    s2 += __shfl_xor(s2, 2, 64);
    if (q == 0) {
        pmax[(size_t)n * VT + bm] = m2;
        psum[(size_t)n * VT + bm] = s2;
    }
}

// ---------------------------------------------------------------------------
// K4b: combine per-block partials -> lse[n]. grid 64, block 256. (R0 verbatim)
// ---------------------------------------------------------------------------
__global__ __launch_bounds__(256) void k_lse(
    const float* __restrict__ pmax, const float* __restrict__ psum,
    float* __restrict__ lse)
{
    __shared__ float rm[4], rs[4];
    const int n = blockIdx.x, t = threadIdx.x;
    float m0 = (t < VT) ? pmax[(size_t)n * VT + t] : -1e30f;
    float m1 = (t + 256 < VT) ? pmax[(size_t)n * VT + t + 256] : -1e30f;
    float mm = fmaxf(m0, m1);
#pragma unroll
    for (int off = 32; off > 0; off >>= 1) mm = fmaxf(mm, __shfl_xor(mm, off, 64));
    if ((t & 63) == 0) rm[t >> 6] = mm;
    __syncthreads();
    float m = fmaxf(fmaxf(rm[0], rm[1]), fmaxf(rm[2], rm[3]));

    float s = 0.f;
    if (t < VT)       s += psum[(size_t)n * VT + t] * __expf(m0 - m);
    if (t + 256 < VT) s += psum[(size_t)n * VT + t + 256] * __expf(m1 - m);
#pragma unroll
    for (int off = 32; off > 0; off >>= 1) s += __shfl_xor(s, off, 64);
    if ((t & 63) == 0) rs[t >> 6] = s;
    __syncthreads();
    if (t == 0) {
        float st = rs[0] + rs[1] + rs[2] + rs[3];
        lse[n] = m + __logf(st);
    }
}

// ---------------------------------------------------------------------------
// K4c: normalize logits in place. grid (32, 64), block 256, float4. (R0 verbatim)
// ---------------------------------------------------------------------------
__global__ __launch_bounds__(256) void k_norm(
    float* __restrict__ dlogits, const float* __restrict__ lse)
{
    const int n = blockIdx.y;
    const int t4 = blockIdx.x * 256 + threadIdx.x;   // float4 index in row
    if (t4 >= V / 4) return;
    float s = lse[n];
    float4* p = (float4*)(dlogits + (size_t)n * V) + t4;
    float4 v = *p;
    v.x -= s; v.y -= s; v.z -= s; v.w -= s;
    *p = v;
}

// ---------------------------------------------------------------------------
extern "C" void kernel_launch(void* const* d_in, const int* in_sizes, int n_in,
                              void* d_out, int out_size, void* d_ws, size_t ws_size,
                              hipStream_t stream)
{
    const int* ids   = (const int*)d_in[0];
    const float* h   = (const float*)d_in[1];
    const float* c   = (const float*)d_in[2];
    const float* enc = (const float*)d_in[3];
    const unsigned char* mask = (const unsigned char*)d_in[4];
    const float* embW = (const float*)d_in[5];
    const float* w_ih = (const float*)d_in[6];
    const float* b_ih = (const float*)d_in[7];
    const float* w_hh = (const float*)d_in[8];
    const float* b_hh = (const float*)d_in[9];
    const float* Wh   = (const float*)d_in[10];
    const float* Ws   = (const float*)d_in[11];
    const float* av   = (const float*)d_in[12];
    const float* h2oW = (const float*)d_in[13];
    const float* h2ob = (const float*)d_in[14];

    float* out = (float*)d_out;
    float* ws = (float*)d_ws;
    // layout (floats):
    float* gates_p = ws;                          // 8*64*2048 = 1048576
    float* sproj   = ws + 1048576;                // 32768
    float* scorep  = ws + 1048576 + 32768;        // 65536
    unsigned short* xb = (unsigned short*)(ws + 1048576 + 32768 + 65536);  // 64x1024 bf16
    // pmax/psum/lse overlay the gates_p region (dead after k_lstm_pw)
    float* pmax = ws;                             // 64*500 = 32000
    float* psum = ws + 32000;                     // 32000
    float* lse  = ws + 64000;                     // 64

    k_gates<<<dim3(32, 8), 256, 0, stream>>>(ids, h, embW, w_ih, w_hh, gates_p);
    k_lstm_pw<<<128, 256, 0, stream>>>(gates_p, b_ih, b_hh, c, out, xb);
    k_sproj<<<128, 256, 0, stream>>>(out, Wh, sproj);
    k_score_gemm<<<dim3(128, 8), 256, 0, stream>>>(enc, Ws, sproj, av, scorep);
    k_softmax_ctx<<<64, 512, 0, stream>>>(scorep, mask, enc, xb);
    k_logits<<<VT, 256, 0, stream>>>(h2oW, xb, h2ob, out, pmax, psum);
    k_lse<<<64, 256, 0, stream>>>(pmax, psum, lse);
    k_norm<<<dim3(32, 64), 256, 0, stream>>>(out, lse);
}

// Round 3
// 342.373 us; speedup vs baseline: 1.1152x; 1.0260x over previous
//
#include <hip/hip_runtime.h>
#include <hip/hip_bf16.h>
#include <math.h>

#define V 32000
#define E 512
#define H 512
#define N 64
#define L 128
#define NV (N*V)
#define NH (N*H)
#define MTOT (N*L)   // 8192 rows of the score GEMM
#define VT 500       // v-tiles (of 64) in k_logits

typedef short  s8v  __attribute__((ext_vector_type(8)));   // 8 bf16 (4 VGPRs)
typedef float  f4v  __attribute__((ext_vector_type(4)));

__device__ __forceinline__ float sigf(float x) { return 1.0f / (1.0f + __expf(-x)); }

// fp32 -> bf16 round-to-nearest-even (scalar path, non-hot kernels)
__device__ __forceinline__ unsigned short f2bf(float f) {
    unsigned int u = __float_as_uint(f);
    unsigned int r = u + 0x7FFFu + ((u >> 16) & 1u);
    return (unsigned short)(r >> 16);
}

// pair fp32 -> packed 2xbf16, RNE; compiler emits v_cvt_pk_bf16_f32
__device__ __forceinline__ unsigned int cvt2bf(float x, float y) {
    __hip_bfloat162 h2 = __float22bfloat162_rn(make_float2(x, y));
    unsigned int r;
    __builtin_memcpy(&r, &h2, 4);
    return r;
}

// 8 fp32 -> 4 packed bf16 pairs (one 16B LDS store)
__device__ __forceinline__ uint4 pack_q(float4 lo, float4 hi) {
    uint4 q;
    q.x = cvt2bf(lo.x, lo.y); q.y = cvt2bf(lo.z, lo.w);
    q.z = cvt2bf(hi.x, hi.y); q.w = cvt2bf(hi.z, hi.w);
    return q;
}

// ---------------------------------------------------------------------------
// K1: LSTM gate GEMM, k-split partials. grid (32 j-tiles, 8 k-splits of 128),
// block 256 = 64 j-lanes x 4 n-groups(16 n). LDS 32 KB.  (unchanged)
// ---------------------------------------------------------------------------
__global__ __launch_bounds__(256) void k_gates(
    const int* __restrict__ ids, const float* __restrict__ hprev,
    const float* __restrict__ embW, const float* __restrict__ w_ih,
    const float* __restrict__ w_hh, float* __restrict__ gates_p)
{
    __shared__ __align__(16) float xs[64 * 128];  // 32 KB
    const int bx = blockIdx.x;   // j-tile
    const int ks = blockIdx.y;   // k-split (0..7): 0-3 emb, 4-7 h
    const int tid = threadIdx.x;
    const bool emb_part = (ks < 4);
    const int koff = (ks & 3) * 128;

    for (int i = tid; i < 64 * 32; i += 256) {
        int n = i >> 5, kk4 = i & 31;
        float4 x4;
        if (emb_part)
            x4 = ((const float4*)(embW + (size_t)ids[n] * E + koff))[kk4];
        else
            x4 = ((const float4*)(hprev + (size_t)n * H + koff))[kk4];
        ((float4*)xs)[n * 32 + kk4] = x4;
    }
    __syncthreads();

    const int jl = tid & 63;
    const int ng = tid >> 6;
    const int j = bx * 64 + jl;
    const int nb = ng * 16;
    const float* wrow = (emb_part ? w_ih : w_hh) + (size_t)j * 512 + koff;

    float acc[16];
#pragma unroll
    for (int i = 0; i < 16; ++i) acc[i] = 0.f;

    for (int e4 = 0; e4 < 32; ++e4) {
        float4 w4 = ((const float4*)wrow)[e4];
#pragma unroll
        for (int i = 0; i < 16; ++i) {
            float4 x4 = ((const float4*)xs)[(nb + i) * 32 + e4];  // wave-uniform broadcast
            acc[i] += w4.x * x4.x + w4.y * x4.y + w4.z * x4.z + w4.w * x4.w;
        }
    }
#pragma unroll
    for (int i = 0; i < 16; ++i)
        gates_p[(size_t)ks * (64 * 2048) + (size_t)(nb + i) * 2048 + j] = acc[i];
}

// ---------------------------------------------------------------------------
// K1b: combine partials + biases, LSTM pointwise.  (unchanged)
// ---------------------------------------------------------------------------
__global__ __launch_bounds__(256) void k_lstm_pw(
    const float* __restrict__ gates_p, const float* __restrict__ b_ih,
    const float* __restrict__ b_hh, const float* __restrict__ cprev,
    float* __restrict__ out, unsigned short* __restrict__ xb)
{
    int i = blockIdx.x * 256 + threadIdx.x;  // 0..32767
    if (i >= NH) return;
    int n = i >> 9, k = i & 511;
    float g[4];
#pragma unroll
    for (int q = 0; q < 4; ++q) {
        int j = q * 512 + k;
        float s = b_ih[j] + b_hh[j];
#pragma unroll
        for (int ks = 0; ks < 8; ++ks)
            s += gates_p[(size_t)ks * (64 * 2048) + (size_t)n * 2048 + j];
        g[q] = s;
    }
    float ig = sigf(g[0]), fg = sigf(g[1]), gg = tanhf(g[2]), og = sigf(g[3]);
    float ct = fg * cprev[i] + ig * gg;
    float ht = og * tanhf(ct);
    out[NV + i] = ht;
    out[NV + NH + i] = ct;
    xb[(size_t)n * 1024 + k] = f2bf(ht);
}

// ---------------------------------------------------------------------------
// K2a: sproj = h_t @ Wh.T  (64 x 512, K=512). grid 128, block 256. (unchanged)
// ---------------------------------------------------------------------------
__global__ __launch_bounds__(256) void k_sproj(
    const float* __restrict__ out, const float* __restrict__ Wh,
    float* __restrict__ sproj)
{
    __shared__ __align__(16) float xs[512];
    int n = blockIdx.x >> 1;
    int h = (blockIdx.x & 1) * 256 + threadIdx.x;
    const float* ht = out + NV + (size_t)n * 512;
    for (int i = threadIdx.x; i < 512; i += 256) xs[i] = ht[i];
    __syncthreads();
    const float* wrow = Wh + (size_t)h * 512;
    float acc = 0.f;
    for (int e4 = 0; e4 < 128; ++e4) {
        float4 w4 = ((const float4*)wrow)[e4];
        float4 x4 = ((const float4*)xs)[e4];
        acc += w4.x * x4.x + w4.y * x4.y + w4.z * x4.z + w4.w * x4.w;
    }
    sproj[(size_t)n * 512 + h] = acc;
}

// ---------------------------------------------------------------------------
// K2b: score GEMM via bf16 MFMA + fused tanh/v-dot epilogue. Staged-LDS
// structure with cvt_pk packing. Grid SWAPPED to (8 bh, 128 bm) so the 8
// blocks sharing an enc A-tile are dispatch-adjacent (L2/L3 locality).
// ---------------------------------------------------------------------------
__global__ __launch_bounds__(256) void k_score_gemm(
    const float* __restrict__ enc, const float* __restrict__ Ws,
    const float* __restrict__ sproj, const float* __restrict__ av,
    float* __restrict__ scorep)
{
    __shared__ __align__(16) short As[64 * 72];
    __shared__ __align__(16) short Bs[64 * 72];
    __shared__ float sred[64];

    const int bh = blockIdx.x, bm = blockIdx.y;   // bh fastest-varying
    const int tid = threadIdx.x;
    const int w = tid >> 6, l = tid & 63;
    const int wave_m = (w >> 1) * 32, wave_h = (w & 1) * 32;
    const int lq = l >> 4, lr = l & 15;

    if (tid < 64) sred[tid] = 0.f;

    f4v acc[2][2];
#pragma unroll
    for (int i = 0; i < 2; ++i)
#pragma unroll
        for (int j = 0; j < 2; ++j) acc[i][j] = (f4v)0.f;

    for (int kt = 0; kt < 8; ++kt) {
        __syncthreads();
#pragma unroll
        for (int r = 0; r < 2; ++r) {
            int idx = (r * 256 + tid) * 8;
            int row = idx >> 6, col = idx & 63;
            const float* sa = enc + (size_t)(bm * 64 + row) * 512 + kt * 64 + col;
            const float* sb = Ws  + (size_t)(bh * 64 + row) * 512 + kt * 64 + col;
            float4 a0 = *(const float4*)sa, a1 = *(const float4*)(sa + 4);
            float4 b0 = *(const float4*)sb, b1 = *(const float4*)(sb + 4);
            *(uint4*)(As + row * 72 + col) = pack_q(a0, a1);
            *(uint4*)(Bs + row * 72 + col) = pack_q(b0, b1);
        }
        __syncthreads();

#pragma unroll
        for (int ks = 0; ks < 2; ++ks) {
            s8v a_frag[2], b_frag[2];
#pragma unroll
            for (int i = 0; i < 2; ++i)
                a_frag[i] = *(const s8v*)(As + (wave_m + 16 * i + lr) * 72 + ks * 32 + lq * 8);
#pragma unroll
            for (int j = 0; j < 2; ++j)
                b_frag[j] = *(const s8v*)(Bs + (wave_h + 16 * j + lr) * 72 + ks * 32 + lq * 8);
#pragma unroll
            for (int i = 0; i < 2; ++i)
#pragma unroll
                for (int j = 0; j < 2; ++j)
                    acc[i][j] = __builtin_amdgcn_mfma_f32_16x16x32_bf16(
                        a_frag[i], b_frag[j], acc[i][j], 0, 0, 0);
        }
    }
    __syncthreads();

    const int hc0 = bh * 64 + wave_h + lr;
#pragma unroll
    for (int i = 0; i < 2; ++i) {
#pragma unroll
        for (int reg = 0; reg < 4; ++reg) {
            int m_local = wave_m + 16 * i + lq * 4 + reg;
            int m = bm * 64 + m_local;
            int n = m >> 7;
            float p = 0.f;
#pragma unroll
            for (int j = 0; j < 2; ++j) {
                int hc = hc0 + 16 * j;
                float val = acc[i][j][reg] + sproj[(size_t)n * 512 + hc];
                p += tanhf(val) * av[hc];
            }
            p += __shfl_xor(p, 1, 64);
            p += __shfl_xor(p, 2, 64);
            p += __shfl_xor(p, 4, 64);
            p += __shfl_xor(p, 8, 64);
            if (lr == 0) atomicAdd(&sred[m_local], p);
        }
    }
    __syncthreads();
    if (tid < 64)
        scorep[(size_t)bh * MTOT + bm * 64 + tid] = sred[tid];
}

// ---------------------------------------------------------------------------
// K2c: combine score partials, mask, softmax over L, context. 4-way split
// over H for memory parallelism (softmax recomputed redundantly per block).
// grid (64 n, 4 h-chunks), block 128.
// ---------------------------------------------------------------------------
__global__ __launch_bounds__(128) void k_softmax_ctx(
    const float* __restrict__ scorep, const unsigned char* __restrict__ mask,
    const float* __restrict__ enc, unsigned short* __restrict__ xb)
{
    __shared__ float wl[128];
    __shared__ float red[4];
    const int n = blockIdx.x, hc = blockIdx.y, t = threadIdx.x;  // t = l index

    float s = 0.f;
#pragma unroll
    for (int q = 0; q < 8; ++q)
        s += scorep[(size_t)q * MTOT + n * 128 + t];
    if (mask[(size_t)n * 128 + t]) s = -1e30f;

    float m = s;
#pragma unroll
    for (int off = 32; off > 0; off >>= 1) m = fmaxf(m, __shfl_xor(m, off, 64));
    if ((t & 63) == 0) red[t >> 6] = m;
    __syncthreads();
    m = fmaxf(red[0], red[1]);
    float e = __expf(s - m);
    float ss = e;
#pragma unroll
    for (int off = 32; off > 0; off >>= 1) ss += __shfl_xor(ss, off, 64);
    if ((t & 63) == 0) red[2 + (t >> 6)] = ss;
    __syncthreads();
    float inv = 1.0f / (red[2] + red[3]);
    wl[t] = e * inv;
    __syncthreads();

    const float* encn = enc + (size_t)n * (L * H) + hc * 128 + t;
    float acc = 0.f;
#pragma unroll 8
    for (int ll = 0; ll < 128; ++ll)
        acc += wl[ll] * encn[(size_t)ll * 512];
    xb[(size_t)n * 1024 + 512 + hc * 128 + t] = f2bf(acc);
}

// ---------------------------------------------------------------------------
// K4a: logits GEMM via bf16 MFMA, C^T view: M=v(32000), N=n(64), K=1024.
// v3: 512 threads = 8 waves; waves 0-3 compute K[0:512], waves 4-7 compute
// K[512:1024], each group staging into its own As/Bs half (LDS 54 KB,
// 2 blocks/CU). Doubles waves/CU 8->16 and outstanding loads ~2x — the
// barrier-drain stalls of one wave overlap another wave's loads (m114
// mechanism). Halves combined through the cs transpose buffer.
// Epilogue (threads 0-255) unchanged.
// ---------------------------------------------------------------------------
__global__ __launch_bounds__(512) void k_logits(
    const float* __restrict__ h2oW, const unsigned short* __restrict__ xb,
    const float* __restrict__ h2ob, float* __restrict__ dlogits,
    float* __restrict__ pmax, float* __restrict__ psum)
{
    __shared__ __align__(16) short As[2][64 * 72];   // 18432 B
    __shared__ __align__(16) short Bs[2][64 * 72];   // 18432 B
    __shared__ __align__(16) float cs[64 * 68];      // 17408 B

    const int bm = blockIdx.x;   // v-tile
    const int tid = threadIdx.x;
    const int g = tid >> 8;            // K-half (0 or 1)
    const int tl = tid & 255;          // index within group
    const int w2 = (tid >> 6) & 3;     // wave within group
    const int l = tid & 63;
    const int wave_m = (w2 & 1) * 32, wave_n = (w2 >> 1) * 32;
    const int lq = l >> 4, lr = l & 15;

    const int arow = tl >> 2;            // 0..63
    const int acol = (tl & 3) * 16;      // 0,16,32,48
    const float* aptr = h2oW + (size_t)(bm * 64 + arow) * 1024 + g * 512 + acol;
    const unsigned short* bptr = xb + (size_t)arow * 1024 + g * 512 + acol;

    short* Asg = As[g];
    short* Bsg = Bs[g];

    f4v acc[2][2];
#pragma unroll
    for (int i = 0; i < 2; ++i)
#pragma unroll
        for (int j = 0; j < 2; ++j) acc[i][j] = (f4v)0.f;

#pragma unroll 1
    for (int kt = 0; kt < 8; ++kt) {
        if (kt) __syncthreads();
        const float* ap = aptr + kt * 64;
        const unsigned short* bp = bptr + kt * 64;
        float4 a0 = ((const float4*)ap)[0], a1 = ((const float4*)ap)[1];
        float4 a2 = ((const float4*)ap)[2], a3 = ((const float4*)ap)[3];
        uint4 b0 = *(const uint4*)bp, b1 = *(const uint4*)(bp + 8);
        *(uint4*)(Asg + arow * 72 + acol)     = pack_q(a0, a1);
        *(uint4*)(Asg + arow * 72 + acol + 8) = pack_q(a2, a3);
        *(uint4*)(Bsg + arow * 72 + acol)     = b0;
        *(uint4*)(Bsg + arow * 72 + acol + 8) = b1;
        __syncthreads();

#pragma unroll
        for (int ks = 0; ks < 2; ++ks) {
            s8v a_frag[2], b_frag[2];
#pragma unroll
            for (int i = 0; i < 2; ++i)
                a_frag[i] = *(const s8v*)(Asg + (wave_m + 16 * i + lr) * 72 + ks * 32 + lq * 8);
#pragma unroll
            for (int j = 0; j < 2; ++j)
                b_frag[j] = *(const s8v*)(Bsg + (wave_n + 16 * j + lr) * 72 + ks * 32 + lq * 8);
#pragma unroll
            for (int i = 0; i < 2; ++i)
#pragma unroll
                for (int j = 0; j < 2; ++j)
                    acc[i][j] = __builtin_amdgcn_mfma_f32_16x16x32_bf16(
                        a_frag[i], b_frag[j], acc[i][j], 0, 0, 0);
        }
    }
    __syncthreads();

    // combine K-halves through the cs transpose buffer
    if (g == 0) {
#pragma unroll
        for (int i = 0; i < 2; ++i)
#pragma unroll
            for (int j = 0; j < 2; ++j)
#pragma unroll
                for (int reg = 0; reg < 4; ++reg)
                    cs[(wave_n + 16 * j + lr) * 68 + wave_m + 16 * i + lq * 4 + reg] = acc[i][j][reg];
    }
    __syncthreads();
    if (g == 1) {
#pragma unroll
        for (int i = 0; i < 2; ++i)
#pragma unroll
            for (int j = 0; j < 2; ++j)
#pragma unroll
                for (int reg = 0; reg < 4; ++reg)
                    cs[(wave_n + 16 * j + lr) * 68 + wave_m + 16 * i + lq * 4 + reg] += acc[i][j][reg];
    }
    __syncthreads();

    // coalesced stores + log-softmax partials (threads 0-255)
    if (tid < 256) {
        const int n = tid >> 2, q = tid & 3;
        const int v0 = bm * 64 + q * 16;
        float4 vals[4];
        float m_loc = -1e30f;
#pragma unroll
        for (int k = 0; k < 4; ++k) {
            float4 cv = *(const float4*)(cs + n * 68 + q * 16 + 4 * k);
            float4 bv = *(const float4*)(h2ob + v0 + 4 * k);
            cv.x += bv.x; cv.y += bv.y; cv.z += bv.z; cv.w += bv.w;
            vals[k] = cv;
            *(float4*)(dlogits + (size_t)n * V + v0 + 4 * k) = cv;
            m_loc = fmaxf(m_loc, fmaxf(fmaxf(cv.x, cv.y), fmaxf(cv.z, cv.w)));
        }
        float s_loc = 0.f;
#pragma unroll
        for (int k = 0; k < 4; ++k) {
            s_loc += __expf(vals[k].x - m_loc) + __expf(vals[k].y - m_loc)
                   + __expf(vals[k].z - m_loc) + __expf(vals[k].w - m_loc);
        }
        // combine the 4 q-lanes (adjacent lanes) of row n
        float m2 = fmaxf(m_loc, __shfl_xor(m_loc, 1, 64));
        m2 = fmaxf(m2, __shfl_xor(m2, 2, 64));
        s_loc *= __expf(m_loc - m2);
        float s2 = s_loc + __shfl_xor(s_loc, 1, 64);
        s2 += __shfl_xor(s2, 2, 64);
        if (q == 0) {
            pmax[(size_t)n * VT + bm] = m2;
            psum[(size_t)n * VT + bm] = s2;
        }
    }
}

// ---------------------------------------------------------------------------
// K4b: combine per-block partials -> lse[n]. grid 64, block 256. (unchanged)
// ---------------------------------------------------------------------------
__global__ __launch_bounds__(256) void k_lse(
    const float* __restrict__ pmax, const float* __restrict__ psum,
    float* __restrict__ lse)
{
    __shared__ float rm[4], rs[4];
    const int n = blockIdx.x, t = threadIdx.x;
    float m0 = (t < VT) ? pmax[(size_t)n * VT + t] : -1e30f;
    float m1 = (t + 256 < VT) ? pmax[(size_t)n * VT + t + 256] : -1e30f;
    float mm = fmaxf(m0, m1);
#pragma unroll
    for (int off = 32; off > 0; off >>= 1) mm = fmaxf(mm, __shfl_xor(mm, off, 64));
    if ((t & 63) == 0) rm[t >> 6] = mm;
    __syncthreads();
    float m = fmaxf(fmaxf(rm[0], rm[1]), fmaxf(rm[2], rm[3]));

    float s = 0.f;
    if (t < VT)       s += psum[(size_t)n * VT + t] * __expf(m0 - m);
    if (t + 256 < VT) s += psum[(size_t)n * VT + t + 256] * __expf(m1 - m);
#pragma unroll
    for (int off = 32; off > 0; off >>= 1) s += __shfl_xor(s, off, 64);
    if ((t & 63) == 0) rs[t >> 6] = s;
    __syncthreads();
    if (t == 0) {
        float st = rs[0] + rs[1] + rs[2] + rs[3];
        lse[n] = m + __logf(st);
    }
}

// ---------------------------------------------------------------------------
// K4c: normalize logits in place. grid (32, 64), block 256, float4. (unchanged)
// ---------------------------------------------------------------------------
__global__ __launch_bounds__(256) void k_norm(
    float* __restrict__ dlogits, const float* __restrict__ lse)
{
    const int n = blockIdx.y;
    const int t4 = blockIdx.x * 256 + threadIdx.x;   // float4 index in row
    if (t4 >= V / 4) return;
    float s = lse[n];
    float4* p = (float4*)(dlogits + (size_t)n * V) + t4;
    float4 v = *p;
    v.x -= s; v.y -= s; v.z -= s; v.w -= s;
    *p = v;
}

// ---------------------------------------------------------------------------
extern "C" void kernel_launch(void* const* d_in, const int* in_sizes, int n_in,
                              void* d_out, int out_size, void* d_ws, size_t ws_size,
                              hipStream_t stream)
{
    const int* ids   = (const int*)d_in[0];
    const float* h   = (const float*)d_in[1];
    const float* c   = (const float*)d_in[2];
    const float* enc = (const float*)d_in[3];
    const unsigned char* mask = (const unsigned char*)d_in[4];
    const float* embW = (const float*)d_in[5];
    const float* w_ih = (const float*)d_in[6];
    const float* b_ih = (const float*)d_in[7];
    const float* w_hh = (const float*)d_in[8];
    const float* b_hh = (const float*)d_in[9];
    const float* Wh   = (const float*)d_in[10];
    const float* Ws   = (const float*)d_in[11];
    const float* av   = (const float*)d_in[12];
    const float* h2oW = (const float*)d_in[13];
    const float* h2ob = (const float*)d_in[14];

    float* out = (float*)d_out;
    float* ws = (float*)d_ws;
    // layout (floats):
    float* gates_p = ws;                          // 8*64*2048 = 1048576
    float* sproj   = ws + 1048576;                // 32768
    float* scorep  = ws + 1048576 + 32768;        // 65536
    unsigned short* xb = (unsigned short*)(ws + 1048576 + 32768 + 65536);  // 64x1024 bf16
    // pmax/psum/lse overlay the gates_p region (dead after k_lstm_pw)
    float* pmax = ws;                             // 64*500 = 32000
    float* psum = ws + 32000;                     // 32000
    float* lse  = ws + 64000;                     // 64

    k_gates<<<dim3(32, 8), 256, 0, stream>>>(ids, h, embW, w_ih, w_hh, gates_p);
    k_lstm_pw<<<128, 256, 0, stream>>>(gates_p, b_ih, b_hh, c, out, xb);
    k_sproj<<<128, 256, 0, stream>>>(out, Wh, sproj);
    k_score_gemm<<<dim3(8, 128), 256, 0, stream>>>(enc, Ws, sproj, av, scorep);
    k_softmax_ctx<<<dim3(64, 4), 128, 0, stream>>>(scorep, mask, enc, xb);
    k_logits<<<VT, 512, 0, stream>>>(h2oW, xb, h2ob, out, pmax, psum);
    k_lse<<<64, 256, 0, stream>>>(pmax, psum, lse);
    k_norm<<<dim3(32, 64), 256, 0, stream>>>(out, lse);
}